// Round 1
// baseline (172.320 us; speedup 1.0000x reference)
//
#include <hip/hip_runtime.h>
#include <hip/hip_bf16.h>

#define TAU_INV_LOG2E 14.4269504088896340736f  // (1/0.1) * log2(e)
#define EPS 1e-8f

typedef __attribute__((ext_vector_type(8))) short bf16x8;
typedef __attribute__((ext_vector_type(4))) float f32x4;

static __device__ __forceinline__ unsigned short f2bf(float f) {
    unsigned int u = __float_as_uint(f);
    unsigned int r = (u + 0x7fffu + ((u >> 16) & 1u)) >> 16;
    return (unsigned short)r;
}

// Kernel 1: L2-normalize rows of x (N x 256 fp32) -> xn (bf16), zero rowsum.
// One wave per row; block = 256 threads = 4 rows.
__global__ __launch_bounds__(256) void normalize_kernel(
    const float* __restrict__ x, unsigned short* __restrict__ xn,
    float* __restrict__ rowsum, int N) {
    const int wave = threadIdx.x >> 6;
    const int lane = threadIdx.x & 63;
    const int row  = blockIdx.x * 4 + wave;
    if (row >= N) return;

    // zero rowsum (ws is poisoned 0xAA before every launch)
    if (threadIdx.x < 4) {
        int rr = blockIdx.x * 4 + threadIdx.x;
        if (rr < N) rowsum[rr] = 0.0f;
    }

    const float4 v = ((const float4*)(x + (size_t)row * 256))[lane];
    float s = v.x * v.x + v.y * v.y + v.z * v.z + v.w * v.w;
    s += __shfl_xor(s, 1);
    s += __shfl_xor(s, 2);
    s += __shfl_xor(s, 4);
    s += __shfl_xor(s, 8);
    s += __shfl_xor(s, 16);
    s += __shfl_xor(s, 32);
    const float norm = fmaxf(sqrtf(s), 1e-12f);
    const float rinv = 1.0f / norm;

    ushort4 o;
    o.x = f2bf(v.x * rinv);
    o.y = f2bf(v.y * rinv);
    o.z = f2bf(v.z * rinv);
    o.w = f2bf(v.w * rinv);
    ((ushort4*)(xn + (size_t)row * 256))[lane] = o;
}

// Kernel 2: fused S = Xn*Xn^T (bf16 MFMA), exp((S)/tau) with zero diagonal,
// row-sum accumulated into rowsum via atomics.
// Block tile 128x128, BK=64, 256 threads = 4 waves in 2x2, each wave 64x64.
__global__ __launch_bounds__(256, 2) void gemm_exp_rowsum_kernel(
    const unsigned short* __restrict__ xn, float* __restrict__ rowsum, int N) {
    const int D = 256;
    const int LDP = 72;  // padded LDS stride (144 B = 36 dwords -> 2-way alias, free)
    __shared__ unsigned short As[128 * 72];
    __shared__ unsigned short Bs[128 * 72];

    const int tid   = threadIdx.x;
    const int wave  = tid >> 6;
    const int lane  = tid & 63;
    const int waveM = wave >> 1;
    const int waveN = wave & 1;
    const int quad  = lane >> 4;
    const int l16   = lane & 15;

    const int iBase = blockIdx.y * 128;
    const int jBase = blockIdx.x * 128;

    f32x4 acc[4][4];
    for (int mt = 0; mt < 4; ++mt)
        for (int nt = 0; nt < 4; ++nt)
            acc[mt][nt] = (f32x4){0.f, 0.f, 0.f, 0.f};

    for (int k0 = 0; k0 < D; k0 += 64) {
        // stage A (rows iBase..+128) and B (rows jBase..+128), cols k0..k0+64
        #pragma unroll
        for (int it = 0; it < 4; ++it) {
            int idx = tid + it * 256;      // 0..1023
            int r   = idx >> 3;            // 0..127
            int c   = (idx & 7) * 8;       // 0..56
            uint4 va = *(const uint4*)(xn + (size_t)(iBase + r) * D + k0 + c);
            uint4 vb = *(const uint4*)(xn + (size_t)(jBase + r) * D + k0 + c);
            *(uint4*)(As + r * LDP + c) = va;
            *(uint4*)(Bs + r * LDP + c) = vb;
        }
        __syncthreads();

        #pragma unroll
        for (int kk = 0; kk < 64; kk += 32) {
            bf16x8 a[4], b[4];
            #pragma unroll
            for (int t = 0; t < 4; ++t) {
                a[t] = *(const bf16x8*)(As + (waveM * 64 + t * 16 + l16) * LDP + kk + quad * 8);
                b[t] = *(const bf16x8*)(Bs + (waveN * 64 + t * 16 + l16) * LDP + kk + quad * 8);
            }
            #pragma unroll
            for (int mt = 0; mt < 4; ++mt)
                #pragma unroll
                for (int nt = 0; nt < 4; ++nt)
                    acc[mt][nt] = __builtin_amdgcn_mfma_f32_16x16x32_bf16(
                        a[mt], b[nt], acc[mt][nt], 0, 0, 0);
        }
        __syncthreads();
    }

    // Epilogue: exp, diagonal mask, row-sum.
    // C/D layout: col = l16, row = quad*4 + reg   [measured m89/m91]
    #pragma unroll
    for (int mt = 0; mt < 4; ++mt) {
        const int gi0 = iBase + waveM * 64 + mt * 16 + quad * 4;
        float s[4] = {0.f, 0.f, 0.f, 0.f};
        #pragma unroll
        for (int nt = 0; nt < 4; ++nt) {
            const int gj = jBase + waveN * 64 + nt * 16 + l16;
            #pragma unroll
            for (int r = 0; r < 4; ++r) {
                float e = __builtin_amdgcn_exp2f(acc[mt][nt][r] * TAU_INV_LOG2E);
                s[r] += (gi0 + r == gj) ? 0.0f : e;
            }
        }
        #pragma unroll
        for (int r = 0; r < 4; ++r) {
            float t = s[r];
            t += __shfl_xor(t, 1);
            t += __shfl_xor(t, 2);
            t += __shfl_xor(t, 4);
            t += __shfl_xor(t, 8);
            if (l16 == 0) atomicAdd(&rowsum[gi0 + r], t);
        }
    }
}

// Kernel 3: loss = mean_i log(rowsum_i/(N-1) + eps). Single block.
__global__ __launch_bounds__(256) void finalize_kernel(
    const float* __restrict__ rowsum, float* __restrict__ out, int N) {
    __shared__ float red[4];
    const float inv = 1.0f / (float)(N - 1);
    float acc = 0.f;
    for (int i = threadIdx.x; i < N; i += 256)
        acc += logf(rowsum[i] * inv + EPS);
    acc += __shfl_xor(acc, 1);
    acc += __shfl_xor(acc, 2);
    acc += __shfl_xor(acc, 4);
    acc += __shfl_xor(acc, 8);
    acc += __shfl_xor(acc, 16);
    acc += __shfl_xor(acc, 32);
    const int wave = threadIdx.x >> 6;
    const int lane = threadIdx.x & 63;
    if (lane == 0) red[wave] = acc;
    __syncthreads();
    if (threadIdx.x == 0) {
        float total = red[0] + red[1] + red[2] + red[3];
        out[0] = total / (float)N;
    }
}

extern "C" void kernel_launch(void* const* d_in, const int* in_sizes, int n_in,
                              void* d_out, int out_size, void* d_ws, size_t ws_size,
                              hipStream_t stream) {
    const float* x = (const float*)d_in[0];
    const int D = 256;
    const int N = in_sizes[0] / D;  // 8192

    unsigned short* xn = (unsigned short*)d_ws;                      // N*D bf16 = 4 MB
    float* rowsum = (float*)((char*)d_ws + (size_t)N * D * sizeof(unsigned short));
    float* out = (float*)d_out;

    normalize_kernel<<<(N + 3) / 4, 256, 0, stream>>>(x, xn, rowsum, N);

    dim3 grid(N / 128, N / 128);
    gemm_exp_rowsum_kernel<<<grid, 256, 0, stream>>>(xn, rowsum, N);

    finalize_kernel<<<1, 256, 0, stream>>>(rowsum, out, N);
}

// Round 2
// 108.729 us; speedup vs baseline: 1.5849x; 1.5849x over previous
//
#include <hip/hip_runtime.h>
#include <hip/hip_bf16.h>
#include <math.h>

#define TAU_INV_LOG2E 14.4269504088896340736f  // (1/0.1) * log2(e)
#define EPS 1e-8f

typedef __attribute__((ext_vector_type(8))) short bf16x8;
typedef __attribute__((ext_vector_type(4))) float f32x4;

static __device__ __forceinline__ unsigned short f2bf(float f) {
    unsigned int u = __float_as_uint(f);
    unsigned int r = (u + 0x7fffu + ((u >> 16) & 1u)) >> 16;
    return (unsigned short)r;
}

static __device__ __forceinline__ void glds16(const void* g, void* l) {
    __builtin_amdgcn_global_load_lds(
        (const __attribute__((address_space(1))) unsigned int*)g,
        (__attribute__((address_space(3))) unsigned int*)l,
        16, 0, 0);
}

// Kernel 1: L2-normalize rows of x (N x 256 fp32) -> xn (bf16), zero rowsum.
// One wave per row; block = 256 threads = 4 rows.
__global__ __launch_bounds__(256) void normalize_kernel(
    const float* __restrict__ x, unsigned short* __restrict__ xn,
    float* __restrict__ rowsum, int N) {
    const int wave = threadIdx.x >> 6;
    const int lane = threadIdx.x & 63;
    const int row  = blockIdx.x * 4 + wave;
    if (row >= N) return;

    if (threadIdx.x < 4) {
        int rr = blockIdx.x * 4 + threadIdx.x;
        if (rr < N) rowsum[rr] = 0.0f;
    }

    const float4 v = ((const float4*)(x + (size_t)row * 256))[lane];
    float s = v.x * v.x + v.y * v.y + v.z * v.z + v.w * v.w;
    s += __shfl_xor(s, 1);
    s += __shfl_xor(s, 2);
    s += __shfl_xor(s, 4);
    s += __shfl_xor(s, 8);
    s += __shfl_xor(s, 16);
    s += __shfl_xor(s, 32);
    const float norm = fmaxf(sqrtf(s), 1e-12f);
    const float rinv = 1.0f / norm;

    ushort4 o;
    o.x = f2bf(v.x * rinv);
    o.y = f2bf(v.y * rinv);
    o.z = f2bf(v.z * rinv);
    o.w = f2bf(v.w * rinv);
    ((ushort4*)(xn + (size_t)row * 256))[lane] = o;
}

// Kernel 2: symmetric fused S = Xn*Xn^T on upper-triangle 128x128 tiles.
// exp(S/tau) with zero diagonal; off-diag tiles contribute row-sums AND
// col-sums (symmetry). global_load_lds(16B) staging, XOR-swizzled LDS.
__global__ __launch_bounds__(256, 3) void gemm_exp_rowsum_kernel(
    const unsigned short* __restrict__ xn, float* __restrict__ rowsum, int N) {
    const int D = 256;
    __shared__ unsigned short As[128 * 64];  // 16 KB, unpadded (DMA layout)
    __shared__ unsigned short Bs[128 * 64];

    const int tid   = threadIdx.x;
    const int wave  = tid >> 6;
    const int lane  = tid & 63;
    const int waveM = wave >> 1;
    const int waveN = wave & 1;
    const int quad  = lane >> 4;
    const int l16   = lane & 15;

    // decode upper-triangle tile pair (bi <= bj) from 1D block index
    const int B = N >> 7;  // 64 tiles per dim
    const int t = blockIdx.x;
    int bi = (int)((2.0 * B + 1.0 -
                    sqrt((2.0 * B + 1.0) * (2.0 * B + 1.0) - 8.0 * (double)t)) * 0.5);
    while (bi > 0 && t < bi * B - (bi * (bi - 1)) / 2) --bi;
    while (t >= (bi + 1) * B - ((bi + 1) * bi) / 2) ++bi;
    const int bj = bi + (t - (bi * B - (bi * (bi - 1)) / 2));
    const bool diag = (bi == bj);

    const int iBase = bi * 128;
    const int jBase = bj * 128;

    f32x4 acc[4][4];
    #pragma unroll
    for (int mt = 0; mt < 4; ++mt)
        #pragma unroll
        for (int nt = 0; nt < 4; ++nt)
            acc[mt][nt] = (f32x4){0.f, 0.f, 0.f, 0.f};

    const int lrow = lane >> 3;            // 0..7 row within 8-row chunk
    const int lsw  = (lane & 7) ^ lrow;    // swizzled 16B col-chunk to fetch

    for (int k0 = 0; k0 < D; k0 += 64) {
        // stage A (+B if off-diag): each wave DMAs 4 chunks of 8 rows x 64 cols
        #pragma unroll
        for (int it = 0; it < 4; ++it) {
            const int q   = wave * 4 + it;        // chunk 0..15
            const int row = q * 8 + lrow;         // 0..127
            glds16(xn + (size_t)(iBase + row) * D + k0 + lsw * 8, As + q * 512);
            if (!diag)
                glds16(xn + (size_t)(jBase + row) * D + k0 + lsw * 8, Bs + q * 512);
        }
        __syncthreads();

        const unsigned short* Bp = diag ? As : Bs;
        #pragma unroll
        for (int kk = 0; kk < 64; kk += 32) {
            bf16x8 a[4], b[4];
            const int cA = (kk >> 3) + quad;      // 16B col-chunk index
            #pragma unroll
            for (int tt = 0; tt < 4; ++tt) {
                const int rA = waveM * 64 + tt * 16 + l16;
                a[tt] = *(const bf16x8*)(As + (rA >> 3) * 512 + (rA & 7) * 64 +
                                          ((cA ^ (rA & 7)) * 8));
                const int rB = waveN * 64 + tt * 16 + l16;
                b[tt] = *(const bf16x8*)(Bp + (rB >> 3) * 512 + (rB & 7) * 64 +
                                          ((cA ^ (rB & 7)) * 8));
            }
            #pragma unroll
            for (int mt = 0; mt < 4; ++mt)
                #pragma unroll
                for (int nt = 0; nt < 4; ++nt)
                    acc[mt][nt] = __builtin_amdgcn_mfma_f32_16x16x32_bf16(
                        a[mt], b[nt], acc[mt][nt], 0, 0, 0);
        }
        __syncthreads();
    }

    // Epilogue. C/D layout: col = l16, row = quad*4 + reg  [m89/m91]
    float rsum[4][4];
    float csum[4] = {0.f, 0.f, 0.f, 0.f};
    #pragma unroll
    for (int mt = 0; mt < 4; ++mt)
        #pragma unroll
        for (int r = 0; r < 4; ++r) rsum[mt][r] = 0.f;

    #pragma unroll
    for (int mt = 0; mt < 4; ++mt) {
        const int gi0 = iBase + waveM * 64 + mt * 16 + quad * 4;
        #pragma unroll
        for (int nt = 0; nt < 4; ++nt) {
            const int gj = jBase + waveN * 64 + nt * 16 + l16;
            #pragma unroll
            for (int r = 0; r < 4; ++r) {
                float e = __builtin_amdgcn_exp2f(acc[mt][nt][r] * TAU_INV_LOG2E);
                if (gi0 + r == gj) e = 0.0f;  // diagonal (only on diag tiles)
                rsum[mt][r] += e;
                csum[nt] += e;
            }
        }
    }
    // row sums -> rowsum[i]
    #pragma unroll
    for (int mt = 0; mt < 4; ++mt) {
        const int gi0 = iBase + waveM * 64 + mt * 16 + quad * 4;
        #pragma unroll
        for (int r = 0; r < 4; ++r) {
            float s = rsum[mt][r];
            s += __shfl_xor(s, 1);
            s += __shfl_xor(s, 2);
            s += __shfl_xor(s, 4);
            s += __shfl_xor(s, 8);
            if (l16 == 0) atomicAdd(&rowsum[gi0 + r], s);
        }
    }
    // col sums -> rowsum[j] (symmetry), off-diag tiles only
    if (!diag) {
        #pragma unroll
        for (int nt = 0; nt < 4; ++nt) {
            float s = csum[nt];
            s += __shfl_xor(s, 16);
            s += __shfl_xor(s, 32);
            if (quad == 0)
                atomicAdd(&rowsum[jBase + waveN * 64 + nt * 16 + l16], s);
        }
    }
}

// Kernel 3: loss = mean_i log(rowsum_i/(N-1) + eps). Single block.
__global__ __launch_bounds__(256) void finalize_kernel(
    const float* __restrict__ rowsum, float* __restrict__ out, int N) {
    __shared__ float red[4];
    const float inv = 1.0f / (float)(N - 1);
    float acc = 0.f;
    for (int i = threadIdx.x; i < N; i += 256)
        acc += logf(rowsum[i] * inv + EPS);
    acc += __shfl_xor(acc, 1);
    acc += __shfl_xor(acc, 2);
    acc += __shfl_xor(acc, 4);
    acc += __shfl_xor(acc, 8);
    acc += __shfl_xor(acc, 16);
    acc += __shfl_xor(acc, 32);
    const int wave = threadIdx.x >> 6;
    const int lane = threadIdx.x & 63;
    if (lane == 0) red[wave] = acc;
    __syncthreads();
    if (threadIdx.x == 0) {
        float total = red[0] + red[1] + red[2] + red[3];
        out[0] = total / (float)N;
    }
}

extern "C" void kernel_launch(void* const* d_in, const int* in_sizes, int n_in,
                              void* d_out, int out_size, void* d_ws, size_t ws_size,
                              hipStream_t stream) {
    const float* x = (const float*)d_in[0];
    const int D = 256;
    const int N = in_sizes[0] / D;  // 8192

    unsigned short* xn = (unsigned short*)d_ws;  // N*D bf16 = 4 MB
    float* rowsum = (float*)((char*)d_ws + (size_t)N * D * sizeof(unsigned short));
    float* out = (float*)d_out;

    normalize_kernel<<<(N + 3) / 4, 256, 0, stream>>>(x, xn, rowsum, N);

    const int B = N / 128;
    const int T = B * (B + 1) / 2;  // 2080 upper-triangle tiles
    gemm_exp_rowsum_kernel<<<T, 256, 0, stream>>>(xn, rowsum, N);

    finalize_kernel<<<1, 256, 0, stream>>>(rowsum, out, N);
}